// Round 1
// baseline (9591.297 us; speedup 1.0000x reference)
//
#include <hip/hip_runtime.h>
#include <math.h>

// Problem constants
#define L 512
#define E 300
#define H 512          // per-direction hidden
#define G4H 2048       // 4*H
#define NTAGS 20
#define START_TAG 18
#define STOP_TAG 19

// Recurrent kernel decomposition: 32 WGs per direction, 512 threads each.
// Each WG owns 16 hidden units (= 64 gate rows). Each thread owns one
// (row, k-slice-of-64) pair of Whh, weights held in 64 VGPRs.
#define GPD 32         // workgroups per direction
#define HPW 16         // hidden units per WG
#define RPW 64         // gate rows per WG (4*HPW)
#define KSL 64         // k-slice per thread (512 / 8)

// Workspace layout (bytes)
#define OFF_XW    0u                       // f32 [2][512][2048]  = 8388608
#define OFF_XBUF  8388608u                 // f32 [512][300]      = 614400
#define OFF_HIST  9003008u                 // f32 [2][512][512]   = 2097152
#define OFF_FEATS 11100160u                // f64 [512][20]       = 81920
#define OFF_BPTR  11182080u                // i32 [512][20]       = 40960
#define OFF_BAR   11223040u                // i32 [64]

// ---------------------------------------------------------------------------
// K0: embedding gather + barrier init
__global__ void k0_gather(const int* __restrict__ sentence,
                          const float* __restrict__ embed,
                          float* __restrict__ xbuf,
                          int* __restrict__ bar) {
    int t = blockIdx.x;
    int tid = threadIdx.x;
    if (t == 0 && tid < 64) bar[tid] = 0;
    size_t row = (size_t)sentence[t] * E;
    for (int k = tid; k < E; k += 256)
        xbuf[(size_t)t * E + k] = embed[row + k];
}

// ---------------------------------------------------------------------------
// K1: xw[dir][t][n] = sum_k x[t][k]*Wih[dir][n][k] + bih[n]+bhh[n]  (f64 acc)
// grid (8 n-tiles, 64 t-tiles, 2 dirs), block 256. Each thread: col n, 8 t's.
__global__ void k1_xw(const float* __restrict__ wih_f, const float* __restrict__ wih_b,
                      const float* __restrict__ bih_f, const float* __restrict__ bhh_f,
                      const float* __restrict__ bih_b, const float* __restrict__ bhh_b,
                      const float* __restrict__ xbuf, float* __restrict__ xw) {
    __shared__ float x8[8][304];
    int tid = threadIdx.x;
    int n   = blockIdx.x * 256 + tid;
    int t0  = blockIdx.y * 8;
    int dir = blockIdx.z;
    const float* wih = dir ? wih_b : wih_f;
    const float* bih = dir ? bih_b : bih_f;
    const float* bhh = dir ? bhh_b : bhh_f;

    for (int r = 0; r < 8; ++r)
        for (int k = tid; k < E; k += 256)
            x8[r][k] = xbuf[(size_t)(t0 + r) * E + k];
    __syncthreads();

    const float* wrow = wih + (size_t)n * E;
    double acc[8];
#pragma unroll
    for (int r = 0; r < 8; ++r) acc[r] = 0.0;

    for (int k = 0; k < E; k += 4) {
        float4 wv = *(const float4*)(wrow + k);
#pragma unroll
        for (int r = 0; r < 8; ++r) {
            float4 xv = *(const float4*)(&x8[r][k]);
            acc[r] = fma((double)wv.x, (double)xv.x, acc[r]);
            acc[r] = fma((double)wv.y, (double)xv.y, acc[r]);
            acc[r] = fma((double)wv.z, (double)xv.z, acc[r]);
            acc[r] = fma((double)wv.w, (double)xv.w, acc[r]);
        }
    }
    double bias = (double)bih[n] + (double)bhh[n];
#pragma unroll
    for (int r = 0; r < 8; ++r)
        xw[((size_t)(dir * L) + (t0 + r)) * G4H + n] = (float)(acc[r] + bias);
}

// ---------------------------------------------------------------------------
// K2: the bidirectional LSTM recurrence (cooperative, custom grid barrier).
__global__ __launch_bounds__(512) void k2_lstm(
    const float* __restrict__ whh_f, const float* __restrict__ whh_b,
    const float* __restrict__ h0, const float* __restrict__ c0,
    const float* __restrict__ xw, float* __restrict__ hist,
    int* __restrict__ bar) {
    const int bid = blockIdx.x;
    const int dir = bid >> 5;       // 0 fwd, 1 bwd
    const int wg  = bid & 31;
    const int tid = threadIdx.x;
    const int lr  = tid >> 3;       // local gate row [0,64)
    const int q   = tid & 7;        // k-slice index
    const int gt  = lr >> 4;        // gate (i,f,g,o)
    const int jj  = lr & 15;        // hidden unit within WG
    const int gr  = gt * H + wg * HPW + jj;   // global gate row
    const int kbase = q * KSL;

    const float* whh = dir ? whh_b : whh_f;
    const float* xwd = xw + (size_t)dir * L * G4H;
    float* histd = hist + (size_t)dir * L * H;

    // Load this thread's 64 weights into registers (one-time).
    float w[KSL];
    {
        const float* wp = whh + (size_t)gr * H + kbase;
#pragma unroll
        for (int i = 0; i < KSL; i += 4) {
            float4 v = *(const float4*)(wp + i);
            w[i] = v.x; w[i + 1] = v.y; w[i + 2] = v.z; w[i + 3] = v.w;
        }
    }

    __shared__ double hs[8 * 66];   // h_prev, padded per k-chunk (bank-safe)
    __shared__ double gbuf[RPW];
    __shared__ double cst[HPW];
    if (tid < HPW) cst[tid] = (double)c0[dir * H + wg * HPW + tid];

    int* cnt = bar + (dir ? 16 : 0);
    int* gen = bar + (dir ? 48 : 32);

    for (int s = 1; s <= L; ++s) {
        const int t = dir ? (L - s) : (s - 1);
        // stage h_prev -> LDS (f64)
        if (tid < 128) {
            const float* hsrc = (s == 1) ? (h0 + dir * H)
                                         : (histd + (size_t)(dir ? t + 1 : t - 1) * H);
            float4 hv = *(const float4*)(hsrc + tid * 4);
            int base = (tid >> 4) * 66 + ((tid * 4) & 63);
            hs[base + 0] = (double)hv.x; hs[base + 1] = (double)hv.y;
            hs[base + 2] = (double)hv.z; hs[base + 3] = (double)hv.w;
        }
        __syncthreads();

        // partial dot over this thread's k-slice
        double acc = 0.0;
        const double* hp = hs + q * 66;
#pragma unroll
        for (int i = 0; i < KSL; i += 2) {
            double2 h2 = *(const double2*)(hp + i);
            acc = fma((double)w[i],     h2.x, acc);
            acc = fma((double)w[i + 1], h2.y, acc);
        }
        acc += __shfl_xor(acc, 1, 8);
        acc += __shfl_xor(acc, 2, 8);
        acc += __shfl_xor(acc, 4, 8);
        if (q == 0) gbuf[lr] = acc;
        __syncthreads();

        // gate update for this WG's 16 hidden units
        if (tid < HPW) {
            const float* xr = xwd + (size_t)t * G4H + wg * HPW + tid;
            double pi = gbuf[tid]      + (double)xr[0];
            double pf = gbuf[16 + tid] + (double)xr[H];
            double pg = gbuf[32 + tid] + (double)xr[2 * H];
            double po = gbuf[48 + tid] + (double)xr[3 * H];
            double ig = 1.0 / (1.0 + exp(-pi));
            double fg = 1.0 / (1.0 + exp(-pf));
            double gg = tanh(pg);
            double og = 1.0 / (1.0 + exp(-po));
            double c  = fg * cst[tid] + ig * gg;
            cst[tid] = c;
            double h = og * tanh(c);
            histd[(size_t)t * H + wg * HPW + tid] = (float)h;
        }
        __syncthreads();   // drains the h stores (vmcnt) WG-wide

        if (s < L) {
            if (tid == 0) {
                __threadfence();   // agent-scope: flush h stores to coherent point
                int old = __hip_atomic_fetch_add(cnt, 1, __ATOMIC_ACQ_REL,
                                                 __HIP_MEMORY_SCOPE_AGENT);
                if (old == GPD * s - 1)
                    __hip_atomic_store(gen, s, __ATOMIC_RELEASE,
                                       __HIP_MEMORY_SCOPE_AGENT);
            }
            while (__hip_atomic_load(gen, __ATOMIC_ACQUIRE,
                                     __HIP_MEMORY_SCOPE_AGENT) < s)
                __builtin_amdgcn_s_sleep(1);
            __syncthreads();
        }
    }
}

// ---------------------------------------------------------------------------
// K3: feats[t][tag] = b_out[tag] + sum_j concat(hf,hb)[t][j]*w_out[tag][j]
// grid 512 (t), block 320 = 20 tags x 16 parts of 64.
__global__ void k3_feats(const float* __restrict__ hist,
                         const float* __restrict__ wout,
                         const float* __restrict__ bout,
                         double* __restrict__ feats) {
    int t = blockIdx.x;
    int tid = threadIdx.x;
    int tag = tid >> 4;       // [0,20)
    int part = tid & 15;
    const float* h0p = hist + (size_t)t * H;               // hf[t]
    const float* h1p = hist + (size_t)L * H + (size_t)t * H; // hb[t]
    int j0 = part * 64;
    double acc = 0.0;
    for (int jj = 0; jj < 64; jj += 4) {
        int j = j0 + jj;
        float4 w4 = *(const float4*)(wout + (size_t)tag * (2 * H) + j);
        float4 h4 = (j < H) ? *(const float4*)(h0p + j)
                            : *(const float4*)(h1p + (j - H));
        acc = fma((double)w4.x, (double)h4.x, acc);
        acc = fma((double)w4.y, (double)h4.y, acc);
        acc = fma((double)w4.z, (double)h4.z, acc);
        acc = fma((double)w4.w, (double)h4.w, acc);
    }
    acc += __shfl_xor(acc, 8, 16);
    acc += __shfl_xor(acc, 4, 16);
    acc += __shfl_xor(acc, 2, 16);
    acc += __shfl_xor(acc, 1, 16);
    if (part == 0) feats[(size_t)t * NTAGS + tag] = acc + (double)bout[tag];
}

// ---------------------------------------------------------------------------
// K4: Viterbi + backtrack, single wave.
__global__ void k4_viterbi(const double* __restrict__ feats,
                           const float* __restrict__ trans,
                           int* __restrict__ bptr,
                           int* __restrict__ out) {
    __shared__ double trl[NTAGS][NTAGS];
    __shared__ double fv[2][NTAGS];
    int tid = threadIdx.x;
    for (int idx = tid; idx < NTAGS * NTAGS; idx += 64)
        trl[idx / NTAGS][idx % NTAGS] = (double)trans[idx];
    if (tid < NTAGS) fv[0][tid] = (tid == START_TAG) ? 0.0 : -10000.0;
    __syncthreads();

    int cur = 0;
    for (int t = 0; t < L; ++t) {
        if (tid < NTAGS) {
            double best = -1.0e300;
            int bp = 0;
#pragma unroll
            for (int pt = 0; pt < NTAGS; ++pt) {
                double sc = fv[cur][pt] + trl[tid][pt];
                if (sc > best) { best = sc; bp = pt; }
            }
            fv[cur ^ 1][tid] = best + feats[(size_t)t * NTAGS + tid];
            bptr[t * NTAGS + tid] = bp;
        }
        __syncthreads();
        cur ^= 1;
    }
    if (tid == 0) {
        double best = -1.0e300;
        int bt = 0;
        for (int pt = 0; pt < NTAGS; ++pt) {
            double sc = fv[cur][pt] + trl[STOP_TAG][pt];
            if (sc > best) { best = sc; bt = pt; }
        }
        int tag = bt;
        out[L - 1] = tag;
        for (int t = L - 1; t >= 1; --t) {
            tag = bptr[t * NTAGS + tag];
            out[t - 1] = tag;
        }
    }
}

// ---------------------------------------------------------------------------
extern "C" void kernel_launch(void* const* d_in, const int* in_sizes, int n_in,
                              void* d_out, int out_size, void* d_ws, size_t ws_size,
                              hipStream_t stream) {
    const int*   sentence = (const int*)d_in[0];
    const float* embed    = (const float*)d_in[1];
    const float* wih_f    = (const float*)d_in[2];
    const float* whh_f    = (const float*)d_in[3];
    const float* bih_f    = (const float*)d_in[4];
    const float* bhh_f    = (const float*)d_in[5];
    const float* wih_b    = (const float*)d_in[6];
    const float* whh_b    = (const float*)d_in[7];
    const float* bih_b    = (const float*)d_in[8];
    const float* bhh_b    = (const float*)d_in[9];
    const float* h0       = (const float*)d_in[10];
    const float* c0       = (const float*)d_in[11];
    const float* wout     = (const float*)d_in[12];
    const float* bout     = (const float*)d_in[13];
    const float* trans    = (const float*)d_in[14];
    int* out = (int*)d_out;

    char* ws = (char*)d_ws;
    float*  xw    = (float*)(ws + OFF_XW);
    float*  xbuf  = (float*)(ws + OFF_XBUF);
    float*  hist  = (float*)(ws + OFF_HIST);
    double* feats = (double*)(ws + OFF_FEATS);
    int*    bptr  = (int*)(ws + OFF_BPTR);
    int*    bar   = (int*)(ws + OFF_BAR);

    k0_gather<<<L, 256, 0, stream>>>(sentence, embed, xbuf, bar);
    k1_xw<<<dim3(8, 64, 2), 256, 0, stream>>>(wih_f, wih_b, bih_f, bhh_f,
                                              bih_b, bhh_b, xbuf, xw);
    {
        void* args[] = {(void*)&whh_f, (void*)&whh_b, (void*)&h0, (void*)&c0,
                        (void*)&xw, (void*)&hist, (void*)&bar};
        hipLaunchCooperativeKernel((const void*)k2_lstm, dim3(2 * GPD), dim3(512),
                                   args, 0, stream);
    }
    k3_feats<<<L, 320, 0, stream>>>(hist, wout, bout, feats);
    k4_viterbi<<<1, 64, 0, stream>>>(feats, trans, bptr, out);
}

// Round 2
// 1622.895 us; speedup vs baseline: 5.9100x; 5.9100x over previous
//
#include <hip/hip_runtime.h>
#include <math.h>

// Problem constants
#define L 512
#define E 300
#define H 512          // per-direction hidden
#define G4H 2048       // 4*H
#define NTAGS 20
#define START_TAG 18
#define STOP_TAG 19

// K2 decomposition: 32 WGs per direction, 512 threads each.
// Each WG owns 16 hidden units (= 64 gate rows). Each thread owns one
// (row, k-slice-of-64) pair of Whh, weights held in 64 VGPRs.
#define GPD 32         // workgroups per direction
#define HPW 16         // hidden units per WG
#define KSL 64         // k-slice per thread (512 / 8)

// Workspace layout (bytes)
#define OFF_XW    0u                       // f32 [2][512][2048]  = 8388608
#define OFF_XBUF  8388608u                 // f32 [512][300]      = 614400
#define OFF_HIST  9003008u                 // f32 [2][512][512]   = 2097152
#define OFF_FEATS 11100160u                // f64 [512][20]       = 81920
#define OFF_HBUF  11182080u                // u64 [2][2][512]     = 16384

// ---------------------------------------------------------------------------
// K0: embedding gather
__global__ void k0_gather(const int* __restrict__ sentence,
                          const float* __restrict__ embed,
                          float* __restrict__ xbuf) {
    int t = blockIdx.x;
    int tid = threadIdx.x;
    size_t row = (size_t)sentence[t] * E;
    for (int k = tid; k < E; k += 256)
        xbuf[(size_t)t * E + k] = embed[row + k];
}

// ---------------------------------------------------------------------------
// K1: xw[dir][t][n] = sum_k x[t][k]*Wih[dir][n][k] + bih[n]+bhh[n]  (f64 acc)
__global__ void k1_xw(const float* __restrict__ wih_f, const float* __restrict__ wih_b,
                      const float* __restrict__ bih_f, const float* __restrict__ bhh_f,
                      const float* __restrict__ bih_b, const float* __restrict__ bhh_b,
                      const float* __restrict__ xbuf, float* __restrict__ xw) {
    __shared__ float x8[8][304];
    int tid = threadIdx.x;
    int n   = blockIdx.x * 256 + tid;
    int t0  = blockIdx.y * 8;
    int dir = blockIdx.z;
    const float* wih = dir ? wih_b : wih_f;
    const float* bih = dir ? bih_b : bih_f;
    const float* bhh = dir ? bhh_b : bhh_f;

    for (int r = 0; r < 8; ++r)
        for (int k = tid; k < E; k += 256)
            x8[r][k] = xbuf[(size_t)(t0 + r) * E + k];
    __syncthreads();

    const float* wrow = wih + (size_t)n * E;
    double acc[8];
#pragma unroll
    for (int r = 0; r < 8; ++r) acc[r] = 0.0;

    for (int k = 0; k < E; k += 4) {
        float4 wv = *(const float4*)(wrow + k);
#pragma unroll
        for (int r = 0; r < 8; ++r) {
            float4 xv = *(const float4*)(&x8[r][k]);
            acc[r] = fma((double)wv.x, (double)xv.x, acc[r]);
            acc[r] = fma((double)wv.y, (double)xv.y, acc[r]);
            acc[r] = fma((double)wv.z, (double)xv.z, acc[r]);
            acc[r] = fma((double)wv.w, (double)xv.w, acc[r]);
        }
    }
    double bias = (double)bih[n] + (double)bhh[n];
#pragma unroll
    for (int r = 0; r < 8; ++r)
        xw[((size_t)(dir * L) + (t0 + r)) * G4H + n] = (float)(acc[r] + bias);
}

// ---------------------------------------------------------------------------
// K2: bidirectional LSTM recurrence.
// Inter-WG h exchange: RELAXED agent atomics only (plain sc1 loads/stores at
// the coherent point, no buffer_inv/buffer_wbl2). Step tag packed into the
// u64 payload; parity double-buffer makes tag-observation race-free.
__global__ __launch_bounds__(512) void k2_lstm(
    const float* __restrict__ whh_f, const float* __restrict__ whh_b,
    const float* __restrict__ h0, const float* __restrict__ c0,
    const float* __restrict__ xw, float* __restrict__ hist,
    unsigned long long* __restrict__ hbuf) {
    const int bid = blockIdx.x;
    const int dir = bid >> 5;       // 0 fwd, 1 bwd
    const int wg  = bid & 31;
    const int tid = threadIdx.x;
    const int lr  = tid >> 3;       // local gate row [0,64)
    const int q   = tid & 7;        // k-slice index
    const int gt  = lr >> 4;        // gate (i,f,g,o)
    const int jj  = lr & 15;        // hidden unit within WG
    const int gr  = gt * H + wg * HPW + jj;   // global gate row

    const float* whh = dir ? whh_b : whh_f;
    const float* xwd = xw + (size_t)dir * L * G4H;
    float* histd = hist + (size_t)dir * L * H;
    unsigned long long* hb = hbuf + dir * 1024;   // [parity][512]

    // This thread's 64 Whh weights -> registers (one-time).
    float w[KSL];
    {
        const float* wp = whh + (size_t)gr * H + q * KSL;
#pragma unroll
        for (int i = 0; i < KSL; i += 4) {
            float4 v = *(const float4*)(wp + i);
            w[i] = v.x; w[i + 1] = v.y; w[i + 2] = v.z; w[i + 3] = v.w;
        }
    }

    __shared__ double hs[8 * 66];   // h_prev per k-chunk, padded
    __shared__ double gbuf[64];

    double c = 0.0;
    if (tid < HPW) c = (double)c0[dir * H + wg * HPW + tid];

    for (int s = 1; s <= L; ++s) {
        const int t = dir ? (L - s) : (s - 1);

        // ---- acquire h_{s-1}: each thread polls its own tagged slot ----
        if (s == 1) {
            float f = h0[dir * H + tid];
            hs[(tid >> 6) * 66 + (tid & 63)] = (double)f;
        } else {
            unsigned long long* slot = hb + (((s - 1) & 1) << 9) + tid;
            unsigned long long u;
            while (((u = __hip_atomic_load(slot, __ATOMIC_RELAXED,
                                           __HIP_MEMORY_SCOPE_AGENT)) >> 32)
                   != (unsigned)(s - 1))
                __builtin_amdgcn_s_sleep(1);
            hs[(tid >> 6) * 66 + (tid & 63)] =
                (double)__uint_as_float((unsigned)(u & 0xffffffffu));
        }
        __syncthreads();

        // ---- partial dot over this thread's k-slice (f64) ----
        double acc = 0.0;
        const double* hp = hs + q * 66;
#pragma unroll
        for (int i = 0; i < KSL; i += 2) {
            double2 h2 = *(const double2*)(hp + i);
            acc = fma((double)w[i],     h2.x, acc);
            acc = fma((double)w[i + 1], h2.y, acc);
        }
        acc += __shfl_xor(acc, 1, 8);
        acc += __shfl_xor(acc, 2, 8);
        acc += __shfl_xor(acc, 4, 8);
        if (q == 0) gbuf[lr] = acc;
        __syncthreads();

        // ---- gates: wave 0, all four nonlinearities in ONE exp pass ----
        if (tid < 64) {
            int gate = tid >> 4, j = tid & 15;
            double pre = gbuf[tid] +
                (double)xwd[(size_t)t * G4H + gate * H + wg * HPW + j];
            double a  = (gate == 2) ? 2.0 * pre : pre;   // tanh = 2*sig(2x)-1
            double sg = 1.0 / (1.0 + exp(-a));
            double v  = (gate == 2) ? (2.0 * sg - 1.0) : sg;
            double ig = __shfl(v, j);
            double fg = __shfl(v, j + 16);
            double gg = __shfl(v, j + 32);
            double og = __shfl(v, j + 48);
            if (tid < 16) {
                c = fg * c + ig * gg;
                double s2 = 1.0 / (1.0 + exp(-2.0 * c));
                double h  = og * (2.0 * s2 - 1.0);
                float hf = (float)h;
                histd[(size_t)t * H + wg * HPW + tid] = hf;   // for K3
                unsigned long long u =
                    ((unsigned long long)(unsigned)s << 32) |
                    (unsigned long long)__float_as_uint(hf);
                __hip_atomic_store(hb + ((s & 1) << 9) + wg * HPW + tid, u,
                                   __ATOMIC_RELAXED, __HIP_MEMORY_SCOPE_AGENT);
            }
        }
        // next iteration's poll + __syncthreads covers hs/gbuf reuse hazards
    }
}

// ---------------------------------------------------------------------------
// K3: feats[t][tag] = b_out[tag] + sum_j concat(hf,hb)[t][j]*w_out[tag][j]
__global__ void k3_feats(const float* __restrict__ hist,
                         const float* __restrict__ wout,
                         const float* __restrict__ bout,
                         double* __restrict__ feats) {
    int t = blockIdx.x;
    int tid = threadIdx.x;
    int tag = tid >> 4;       // [0,20)
    int part = tid & 15;
    const float* h0p = hist + (size_t)t * H;
    const float* h1p = hist + (size_t)L * H + (size_t)t * H;
    int j0 = part * 64;
    double acc = 0.0;
    for (int jj = 0; jj < 64; jj += 4) {
        int j = j0 + jj;
        float4 w4 = *(const float4*)(wout + (size_t)tag * (2 * H) + j);
        float4 h4 = (j < H) ? *(const float4*)(h0p + j)
                            : *(const float4*)(h1p + (j - H));
        acc = fma((double)w4.x, (double)h4.x, acc);
        acc = fma((double)w4.y, (double)h4.y, acc);
        acc = fma((double)w4.z, (double)h4.z, acc);
        acc = fma((double)w4.w, (double)h4.w, acc);
    }
    acc += __shfl_xor(acc, 8, 16);
    acc += __shfl_xor(acc, 4, 16);
    acc += __shfl_xor(acc, 2, 16);
    acc += __shfl_xor(acc, 1, 16);
    if (part == 0) feats[(size_t)t * NTAGS + tag] = acc + (double)bout[tag];
}

// ---------------------------------------------------------------------------
// K4: Viterbi + backtrack, single wave; backpointers in LDS (u8).
__global__ void k4_viterbi(const double* __restrict__ feats,
                           const float* __restrict__ trans,
                           int* __restrict__ out) {
    __shared__ double trl[NTAGS * NTAGS];
    __shared__ double fv[2][NTAGS];
    __shared__ unsigned char bp[L][NTAGS];
    int tid = threadIdx.x;
    for (int i = tid; i < NTAGS * NTAGS; i += 64)
        trl[i] = (double)trans[i];
    if (tid < NTAGS) fv[0][tid] = (tid == START_TAG) ? 0.0 : -10000.0;
    __syncthreads();

    double nf = (tid < NTAGS) ? feats[tid] : 0.0;   // prefetched feat
    int cur = 0;
    for (int t = 0; t < L; ++t) {
        double f = nf;
        if (tid < NTAGS && t + 1 < L) nf = feats[(size_t)(t + 1) * NTAGS + tid];
        if (tid < NTAGS) {
            double best = -1.0e300;
            int b = 0;
#pragma unroll
            for (int pt = 0; pt < NTAGS; ++pt) {
                double sc = fv[cur][pt] + trl[tid * NTAGS + pt];
                if (sc > best) { best = sc; b = pt; }
            }
            fv[cur ^ 1][tid] = best + f;
            bp[t][tid] = (unsigned char)b;
        }
        __syncthreads();
        cur ^= 1;
    }
    if (tid == 0) {
        double best = -1.0e300;
        int bt = 0;
        for (int pt = 0; pt < NTAGS; ++pt) {
            double sc = fv[cur][pt] + trl[STOP_TAG * NTAGS + pt];
            if (sc > best) { best = sc; bt = pt; }
        }
        int tag = bt;
        out[L - 1] = tag;
        for (int t = L - 1; t >= 1; --t) {
            tag = bp[t][tag];
            out[t - 1] = tag;
        }
    }
}

// ---------------------------------------------------------------------------
extern "C" void kernel_launch(void* const* d_in, const int* in_sizes, int n_in,
                              void* d_out, int out_size, void* d_ws, size_t ws_size,
                              hipStream_t stream) {
    const int*   sentence = (const int*)d_in[0];
    const float* embed    = (const float*)d_in[1];
    const float* wih_f    = (const float*)d_in[2];
    const float* whh_f    = (const float*)d_in[3];
    const float* bih_f    = (const float*)d_in[4];
    const float* bhh_f    = (const float*)d_in[5];
    const float* wih_b    = (const float*)d_in[6];
    const float* whh_b    = (const float*)d_in[7];
    const float* bih_b    = (const float*)d_in[8];
    const float* bhh_b    = (const float*)d_in[9];
    const float* h0       = (const float*)d_in[10];
    const float* c0       = (const float*)d_in[11];
    const float* wout     = (const float*)d_in[12];
    const float* bout     = (const float*)d_in[13];
    const float* trans    = (const float*)d_in[14];
    int* out = (int*)d_out;

    char* ws = (char*)d_ws;
    float*  xw    = (float*)(ws + OFF_XW);
    float*  xbuf  = (float*)(ws + OFF_XBUF);
    float*  hist  = (float*)(ws + OFF_HIST);
    double* feats = (double*)(ws + OFF_FEATS);
    unsigned long long* hbuf = (unsigned long long*)(ws + OFF_HBUF);

    k0_gather<<<L, 256, 0, stream>>>(sentence, embed, xbuf);
    k1_xw<<<dim3(8, 64, 2), 256, 0, stream>>>(wih_f, wih_b, bih_f, bhh_f,
                                              bih_b, bhh_b, xbuf, xw);
    {
        void* args[] = {(void*)&whh_f, (void*)&whh_b, (void*)&h0, (void*)&c0,
                        (void*)&xw, (void*)&hist, (void*)&hbuf};
        hipLaunchCooperativeKernel((const void*)k2_lstm, dim3(2 * GPD), dim3(512),
                                   args, 0, stream);
    }
    k3_feats<<<L, 320, 0, stream>>>(hist, wout, bout, feats);
    k4_viterbi<<<1, 64, 0, stream>>>(feats, trans, out);
}

// Round 3
// 1497.918 us; speedup vs baseline: 6.4031x; 1.0834x over previous
//
#include <hip/hip_runtime.h>
#include <math.h>

// Problem constants
#define L 512
#define E 300
#define H 512          // per-direction hidden
#define G4H 2048       // 4*H
#define NTAGS 20
#define START_TAG 18
#define STOP_TAG 19

#define GPD 32         // workgroups per direction (k2)
#define HPW 16         // hidden units per WG (k2)
#define TR  16         // t-rows per block (k1)

// Workspace layout (bytes)
#define OFF_XW    0u                        // f32 [2][512][2048] = 8388608
#define OFF_HIST  8388608u                  // f32 [2][512][512]  = 2097152
#define OFF_HBUF  10485760u                 // u64 [2][2][512]    = 16384
#define OFF_FEATS 10502144u                 // f32 [512][20]      = 40960

// ---------------------------------------------------------------------------
// K1: xw[dir][t][n] = embed[sent[t]] . wih[n] + bih[n]+bhh[n]   (f32)
// x rows are wave-uniform -> compiler scalarizes to s_load (no LDS, no VALU
// address work). Each thread: 1 col x 16 t-rows. grid(8,32,2), block 256.
__global__ void k1_xw(const int* __restrict__ sentence,
                      const float* __restrict__ embed,
                      const float* __restrict__ wih_f, const float* __restrict__ wih_b,
                      const float* __restrict__ bih_f, const float* __restrict__ bhh_f,
                      const float* __restrict__ bih_b, const float* __restrict__ bhh_b,
                      float* __restrict__ xw) {
    int tid = threadIdx.x;
    int n   = blockIdx.x * 256 + tid;
    int t0  = blockIdx.y * TR;
    int dir = blockIdx.z;
    const float* wih = dir ? wih_b : wih_f;
    const float* bih = dir ? bih_b : bih_f;
    const float* bhh = dir ? bhh_b : bhh_f;
    const float* wrow = wih + (size_t)n * E;

    const float* xr[TR];
#pragma unroll
    for (int r = 0; r < TR; ++r)
        xr[r] = embed + (size_t)sentence[t0 + r] * E;   // uniform (SGPR)

    float acc[TR];
#pragma unroll
    for (int r = 0; r < TR; ++r) acc[r] = 0.f;

    for (int kk = 0; kk < E / 4; ++kk) {
        float4 wv = ((const float4*)wrow)[kk];
#pragma unroll
        for (int r = 0; r < TR; ++r) {
            float4 xv = ((const float4*)xr[r])[kk];     // scalar loads
            acc[r] = fmaf(wv.x, xv.x,
                     fmaf(wv.y, xv.y,
                     fmaf(wv.z, xv.z,
                     fmaf(wv.w, xv.w, acc[r]))));
        }
    }
    float b = bih[n] + bhh[n];
#pragma unroll
    for (int r = 0; r < TR; ++r)
        xw[((size_t)(dir * L) + (t0 + r)) * G4H + n] = acc[r] + b;
}

// ---------------------------------------------------------------------------
// K2: bidirectional LSTM recurrence, f32, LDS-free dot.
// Wave w of each WG owns k-slice [64w,64w+64); lane l owns gate-row l of the
// WG's 64 rows. Thread polls h[64w+l] (== h[tid]) from the tagged global
// buffer; the dot broadcasts h across the wave via readlane (no LDS).
__global__ __launch_bounds__(512) void k2_lstm(
    const float* __restrict__ whh_f, const float* __restrict__ whh_b,
    const float* __restrict__ h0, const float* __restrict__ c0,
    const float* __restrict__ xw, float* __restrict__ hist,
    unsigned long long* __restrict__ hbuf) {
    const int bid = blockIdx.x;
    const int dir = bid >> 5;
    const int wg  = bid & 31;
    const int tid = threadIdx.x;
    const int wv  = tid >> 6;       // wave = k-slice index
    const int l   = tid & 63;       // lane = local gate row
    const int gate = l >> 4;
    const int j    = l & 15;
    const int row  = gate * H + wg * HPW + j;   // global gate row

    const float* whh = dir ? whh_b : whh_f;
    const float* xwd = xw + (size_t)dir * L * G4H;
    float* histd = hist + (size_t)dir * L * H;
    unsigned long long* hb = hbuf + dir * 1024;   // [parity][512]

    // 64 Whh weights -> VGPRs: whh[row][64*wv .. 64*wv+64)
    float w[64];
    {
        const float* wp = whh + (size_t)row * H + wv * 64;
#pragma unroll
        for (int i = 0; i < 64; i += 4) {
            float4 v = *(const float4*)(wp + i);
            w[i] = v.x; w[i + 1] = v.y; w[i + 2] = v.z; w[i + 3] = v.w;
        }
    }

    __shared__ float pbuf[2][8][64];   // [parity][wave][row]; w-major, no conflicts

    float c = (tid < HPW) ? c0[dir * H + wg * HPW + tid] : 0.f;

    for (int s = 1; s <= L; ++s) {
        const int t = dir ? (L - s) : (s - 1);
        float xg = xwd[(size_t)t * G4H + row];   // prefetch; consumed by wave0

        // acquire h_{s-1}[tid]
        float hval;
        if (s == 1) {
            hval = h0[dir * H + tid];
        } else {
            unsigned long long* slot = hb + (((s - 1) & 1) << 9) + tid;
            unsigned long long u;
            while (((u = __hip_atomic_load(slot, __ATOMIC_RELAXED,
                                           __HIP_MEMORY_SCOPE_AGENT)) >> 32)
                   != (unsigned)(s - 1))
                __builtin_amdgcn_s_sleep(1);
            hval = __uint_as_float((unsigned)u);
        }

        // dot: this wave's k-slice lives in this wave's lanes -> readlane bcast
        float acc = 0.f;
#pragma unroll
        for (int i = 0; i < 64; ++i) {
            float hb_i = __uint_as_float(
                (unsigned)__builtin_amdgcn_readlane((int)__float_as_uint(hval), i));
            acc = fmaf(w[i], hb_i, acc);
        }
        pbuf[s & 1][wv][l] = acc;
        __syncthreads();

        // wave 0: reduce 8 partials, gates, produce h_s
        if (tid < 64) {
            float g = 0.f;
#pragma unroll
            for (int p = 0; p < 8; ++p) g += pbuf[s & 1][p][l];
            float pre = g + xg;
            float a  = (gate == 2) ? 2.f * pre : pre;    // tanh = 2*sig(2x)-1
            float sg = 1.f / (1.f + __expf(-a));
            float v  = (gate == 2) ? (2.f * sg - 1.f) : sg;
            float ig = __shfl(v, j);
            float fg = __shfl(v, j + 16);
            float gg = __shfl(v, j + 32);
            float og = __shfl(v, j + 48);
            if (tid < HPW) {
                c = fg * c + ig * gg;
                float tc = 2.f / (1.f + __expf(-2.f * c)) - 1.f;
                float h  = og * tc;
                histd[(size_t)t * H + wg * HPW + tid] = h;
                unsigned long long u =
                    ((unsigned long long)(unsigned)s << 32) |
                    (unsigned long long)__float_as_uint(h);
                __hip_atomic_store(hb + ((s & 1) << 9) + wg * HPW + tid, u,
                                   __ATOMIC_RELAXED, __HIP_MEMORY_SCOPE_AGENT);
            }
        }
        // parity double-buffering of pbuf + the single barrier covers reuse
    }
}

// ---------------------------------------------------------------------------
// K3: feats[t][tag] = b_out[tag] + concat(hf,hb)[t] . w_out[tag]   (f32)
__global__ void k3_feats(const float* __restrict__ hist,
                         const float* __restrict__ wout,
                         const float* __restrict__ bout,
                         float* __restrict__ feats) {
    int t = blockIdx.x;
    int tid = threadIdx.x;
    int tag = tid >> 4;       // [0,20)
    int part = tid & 15;
    const float* h0p = hist + (size_t)t * H;
    const float* h1p = hist + (size_t)L * H + (size_t)t * H;
    int j0 = part * 64;
    float acc = 0.f;
    for (int jj = 0; jj < 64; jj += 4) {
        int j = j0 + jj;
        float4 w4 = *(const float4*)(wout + (size_t)tag * (2 * H) + j);
        float4 h4 = (j < H) ? *(const float4*)(h0p + j)
                            : *(const float4*)(h1p + (j - H));
        acc = fmaf(w4.x, h4.x, fmaf(w4.y, h4.y,
              fmaf(w4.z, h4.z, fmaf(w4.w, h4.w, acc))));
    }
    acc += __shfl_xor(acc, 8, 16);
    acc += __shfl_xor(acc, 4, 16);
    acc += __shfl_xor(acc, 2, 16);
    acc += __shfl_xor(acc, 1, 16);
    if (part == 0) feats[(size_t)t * NTAGS + tag] = acc + bout[tag];
}

// ---------------------------------------------------------------------------
// K4: Viterbi + backtrack. ONE wave, no barriers; fv in registers, transitions
// in registers, backpointers in LDS.
__global__ void k4_viterbi(const float* __restrict__ feats,
                           const float* __restrict__ trans,
                           int* __restrict__ out) {
    __shared__ unsigned char bp[L * NTAGS];
    int lane = threadIdx.x;           // 64 threads
    bool act = lane < NTAGS;

    float trl[NTAGS];
#pragma unroll
    for (int p = 0; p < NTAGS; ++p)
        trl[p] = act ? trans[lane * NTAGS + p] : -1.0e30f;

    float fv = (lane == START_TAG) ? 0.f : -10000.f;
    float nf = act ? feats[lane] : 0.f;

    for (int t = 0; t < L; ++t) {
        float f = nf;
        if (act && t + 1 < L) nf = feats[(size_t)(t + 1) * NTAGS + lane];
        float best = -1.0e30f;
        int b = 0;
#pragma unroll
        for (int p = 0; p < NTAGS; ++p) {
            float sc = __shfl(fv, p) + trl[p];
            if (sc > best) { best = sc; b = p; }   // first-max (ascending p)
        }
        fv = best + f;
        if (act) bp[t * NTAGS + lane] = (unsigned char)b;
    }

    // terminal argmax across lanes (first-max on ties)
    float ts = act ? fv + trans[STOP_TAG * NTAGS + lane] : -1.0e30f;
    int bi = lane;
#pragma unroll
    for (int off = 32; off; off >>= 1) {
        float ov = __shfl_down(ts, off);
        int   oi = __shfl_down(bi, off);
        if (ov > ts) { ts = ov; bi = oi; }
    }
    if (lane == 0) {
        int tag = bi;
        out[L - 1] = tag;
        for (int t = L - 1; t >= 1; --t) {
            tag = bp[t * NTAGS + tag];
            out[t - 1] = tag;
        }
    }
}

// ---------------------------------------------------------------------------
extern "C" void kernel_launch(void* const* d_in, const int* in_sizes, int n_in,
                              void* d_out, int out_size, void* d_ws, size_t ws_size,
                              hipStream_t stream) {
    const int*   sentence = (const int*)d_in[0];
    const float* embed    = (const float*)d_in[1];
    const float* wih_f    = (const float*)d_in[2];
    const float* whh_f    = (const float*)d_in[3];
    const float* bih_f    = (const float*)d_in[4];
    const float* bhh_f    = (const float*)d_in[5];
    const float* wih_b    = (const float*)d_in[6];
    const float* whh_b    = (const float*)d_in[7];
    const float* bih_b    = (const float*)d_in[8];
    const float* bhh_b    = (const float*)d_in[9];
    const float* h0       = (const float*)d_in[10];
    const float* c0       = (const float*)d_in[11];
    const float* wout     = (const float*)d_in[12];
    const float* bout     = (const float*)d_in[13];
    const float* trans    = (const float*)d_in[14];
    int* out = (int*)d_out;

    char* ws = (char*)d_ws;
    float* xw    = (float*)(ws + OFF_XW);
    float* hist  = (float*)(ws + OFF_HIST);
    float* feats = (float*)(ws + OFF_FEATS);
    unsigned long long* hbuf = (unsigned long long*)(ws + OFF_HBUF);

    k1_xw<<<dim3(8, 32, 2), 256, 0, stream>>>(sentence, embed, wih_f, wih_b,
                                              bih_f, bhh_f, bih_b, bhh_b, xw);
    {
        void* args[] = {(void*)&whh_f, (void*)&whh_b, (void*)&h0, (void*)&c0,
                        (void*)&xw, (void*)&hist, (void*)&hbuf};
        hipLaunchCooperativeKernel((const void*)k2_lstm, dim3(2 * GPD), dim3(512),
                                   args, 0, stream);
    }
    k3_feats<<<L, 320, 0, stream>>>(hist, wout, bout, feats);
    k4_viterbi<<<1, 64, 0, stream>>>(feats, trans, out);
}